// Round 3
// baseline (1596.211 us; speedup 1.0000x reference)
//
#include <hip/hip_runtime.h>
#include <hip/hip_bf16.h>

#define Bn 2
#define Tn 1024
#define Dn 1024
#define Hn 16
#define DHn 64
#define FFn 4096
#define Ln 2
#define Vn 32000
#define GM 2048   // B*T rows

typedef unsigned short u16;
typedef __attribute__((ext_vector_type(4))) float f4;
typedef __attribute__((ext_vector_type(4))) unsigned short us4;
typedef __attribute__((ext_vector_type(8))) unsigned short us8;
typedef __attribute__((ext_vector_type(8))) short short8;
typedef __attribute__((ext_vector_type(4))) float f32x4;

__device__ __forceinline__ u16 f2b(float x) {
  union { __hip_bfloat16 h; u16 u; } v; v.h = __float2bfloat16(x); return v.u;
}
__device__ __forceinline__ float b2f(u16 u) {
  union { unsigned int i; float f; } v; v.i = ((unsigned int)u) << 16; return v.f;
}
__device__ __forceinline__ float wred64(float v) {
#pragma unroll
  for (int m = 32; m > 0; m >>= 1) v += __shfl_xor(v, m);
  return v;
}
__device__ __forceinline__ void gload_lds16(const void* g, void* l) {
  __builtin_amdgcn_global_load_lds(
      (const __attribute__((address_space(1))) unsigned int*)g,
      (__attribute__((address_space(3))) unsigned int*)l, 16, 0, 0);
}

// ---------------- RoPE tables ----------------
__global__ void rope_tab_kernel(float* COS, float* SIN) {
  int t = blockIdx.x;            // 1024
  int j = threadIdx.x;           // 64
  float inv = __expf(-(float)(j & 31) * (9.210340371976184f / 32.f)); // 10000^{-i/32}
  float th = (float)t * inv;
  COS[t * 64 + j] = cosf(th);
  SIN[t * 64 + j] = sinf(th);
}

// ---------------- embedding gather ----------------
__global__ __launch_bounds__(256) void embed_kernel(const int* ids, const float* emb, float* x) {
  int g = blockIdx.x;            // 2048
  int id = ids[g];
  const f4* src = (const f4*)(emb + (size_t)id * Dn);
  f4* dst = (f4*)(x + (size_t)g * Dn);
  dst[threadIdx.x] = src[threadIdx.x];
}

// ---------------- quality: DFT coefficients A,B (f=0..127) ----------------
__global__ __launch_bounds__(256) void qa_kernel(const float* x, float* Ac, float* Bc) {
  __shared__ float ct[1024], st[1024];
  int blk = blockIdx.x;          // 256: b*128+f
  int b = blk >> 7, f = blk & 127;
  for (int t = threadIdx.x; t < 1024; t += 256) {
    float u = (float)((f * t) & 1023) * (6.283185307179586f / 1024.f);
    ct[t] = cosf(u); st[t] = sinf(u);
  }
  __syncthreads();
  int d0 = threadIdx.x * 4;
  f4 a = {0.f,0.f,0.f,0.f}, bb = {0.f,0.f,0.f,0.f};
  const float* xb = x + (size_t)b * Tn * Dn + d0;
  for (int t = 0; t < 1024; ++t) {
    f4 xv = *(const f4*)(xb + (size_t)t * Dn);
    float c = ct[t], s = st[t];
    a += xv * c; bb += xv * s;
  }
  size_t o = ((size_t)b * 128 + f) * Dn + d0;
  *(f4*)(Ac + o) = a; *(f4*)(Bc + o) = bb;
}

// ---------------- quality: rho per (b,t) (4 t per block) ----------------
__global__ __launch_bounds__(256) void qr_kernel(const float* Ac, const float* Bc,
                                                 const float* x, float* rho) {
  __shared__ float phc[128][4], phs[128][4];
  __shared__ float redN[4], redD[4];
  int blk = blockIdx.x;          // 512
  int b = blk >> 8, t0 = (blk & 255) * 4;
  int tid = threadIdx.x;
#pragma unroll
  for (int rep = 0; rep < 2; ++rep) {
    int e = rep * 256 + tid;     // 512 entries
    int f = e >> 2, tt = e & 3;
    float u = (float)((f * (t0 + tt)) & 1023) * (6.283185307179586f / 1024.f);
    phc[f][tt] = cosf(u); phs[f][tt] = sinf(u);
  }
  int d0 = tid * 4;
  const float* Ab = Ac + (size_t)b * 128 * Dn + d0;
  const float* Bb = Bc + (size_t)b * 128 * Dn + d0;
  f4 a0 = *(const f4*)Ab;
  float sacc[4][4];
#pragma unroll
  for (int tt = 0; tt < 4; ++tt)
#pragma unroll
    for (int c = 0; c < 4; ++c) sacc[tt][c] = 0.5f * a0[c];
  __syncthreads();
  for (int f = 1; f < 128; ++f) {
    f4 a = *(const f4*)(Ab + (size_t)f * Dn);
    f4 bb = *(const f4*)(Bb + (size_t)f * Dn);
#pragma unroll
    for (int tt = 0; tt < 4; ++tt) {
      float c = phc[f][tt], s = phs[f][tt];
#pragma unroll
      for (int e = 0; e < 4; ++e) sacc[tt][e] += a[e] * c + bb[e] * s;
    }
  }
  int wave = tid >> 6, lane = tid & 63;
  for (int tt = 0; tt < 4; ++tt) {
    f4 xv = *(const f4*)(x + ((size_t)b * Tn + t0 + tt) * Dn + d0);
    float num = 0.f, den = 0.f;
#pragma unroll
    for (int e = 0; e < 4; ++e) {
      float hl = sacc[tt][e] * (2.f / 1024.f);
      num += hl * hl;
      den += xv[e] * xv[e];
    }
    float rn = wred64(num), rd = wred64(den);
    if (lane == 0) { redN[wave] = rn; redD[wave] = rd; }
    __syncthreads();
    if (tid == 0) {
      float n = redN[0] + redN[1] + redN[2] + redN[3];
      float dd = redD[0] + redD[1] + redD[2] + redD[3];
      rho[(size_t)b * Tn + t0 + tt] = n / (dd + 1e-6f);
    }
    __syncthreads();
  }
}

// ---------------- block quality mean + top-8 ----------------
__global__ void topk_kernel(const float* rho, int* sel) {
  __shared__ float bq[32];
  __shared__ int chosen[32];
  int b = blockIdx.x;            // 2
  int m = threadIdx.x;           // 32
  float s = 0.f;
  for (int j = 0; j < 32; ++j) s += rho[(size_t)b * Tn + m * 32 + j];
  bq[m] = s * (1.f / 32.f); chosen[m] = 0;
  __syncthreads();
  if (m == 0) {
    for (int it = 0; it < 8; ++it) {
      float best = -3e38f; int bi = 0;
      for (int mm = 0; mm < 32; ++mm) if (bq[mm] > best) { best = bq[mm]; bi = mm; }
      chosen[bi] = 1; bq[bi] = -3e38f;
    }
  }
  __syncthreads();
  sel[b * 32 + m] = chosen[m];
}

// ---------------- f32 (K,N) -> bf16 (N,K) transpose ----------------
__global__ __launch_bounds__(256) void transpose_to_bf16(const float* src, u16* dst, int K, int N) {
  __shared__ float tile[32][33];
  int n0 = blockIdx.x * 32, k0 = blockIdx.y * 32;
  int c = threadIdx.x & 31, r4 = threadIdx.x >> 5;
#pragma unroll
  for (int rr = 0; rr < 4; ++rr) {
    int r = r4 * 4 + rr;
    tile[r][c] = src[(size_t)(k0 + r) * N + n0 + c];
  }
  __syncthreads();
#pragma unroll
  for (int rr = 0; rr < 4; ++rr) {
    int r = r4 * 4 + rr;
    dst[(size_t)(n0 + r) * K + k0 + c] = f2b(tile[c][r]);
  }
}

// ---------------- RMSNorm (f32 in, bf16 out) ----------------
__global__ __launch_bounds__(256) void rmsnorm_kernel(const float* x, const float* w, u16* out) {
  __shared__ float red[4];
  int g = blockIdx.x;            // 2048
  int tid = threadIdx.x;
  f4 xv = ((const f4*)(x + (size_t)g * Dn))[tid];
  float ss = xv[0]*xv[0] + xv[1]*xv[1] + xv[2]*xv[2] + xv[3]*xv[3];
  ss = wred64(ss);
  if ((tid & 63) == 0) red[tid >> 6] = ss;
  __syncthreads();
  float tot = red[0] + red[1] + red[2] + red[3];
  float r = rsqrtf(tot * (1.f / 1024.f) + 1e-6f);
  f4 wv = ((const f4*)w)[tid];
  us4 o;
#pragma unroll
  for (int e = 0; e < 4; ++e) o[e] = f2b(xv[e] * r * wv[e]);
  *(us4*)(out + (size_t)g * Dn + tid * 4) = o;
}

// ---------------- bf16 MFMA GEMM: C(M,N) = A(M,K) * Bt(N,K)^T (+R) ----------------
// obf: write bf16 (u16) output, no residual; else f32 output with optional residual R.
__global__ __launch_bounds__(256) void gemm_bf16_kernel(
    const u16* __restrict__ A, const u16* __restrict__ Bt,
    void* C, const float* R, int Ni, int Ki, int obf) {
  __shared__ short8 As[1024];    // 128 rows x 64 k (bf16), 16KB
  __shared__ short8 Bs[1024];
  const int tid = threadIdx.x;
  const int wave = tid >> 6, lane = tid & 63;
  const int wr = wave >> 1, wc = wave & 1;
  const int lrow = lane & 15, lkg = lane >> 4;
  const size_t arow0 = (size_t)blockIdx.y * 128;
  const size_t bcol0 = (size_t)blockIdx.x * 128;
  const f32x4 zero4 = {0.f, 0.f, 0.f, 0.f};
  f32x4 acc[4][4];
#pragma unroll
  for (int i = 0; i < 4; ++i)
#pragma unroll
    for (int j = 0; j < 4; ++j) acc[i][j] = zero4;
  const int nK = Ki >> 6;
  for (int kb = 0; kb < nK; ++kb) {
    const size_t k0 = (size_t)kb << 6;
#pragma unroll
    for (int j = 0; j < 4; ++j) {
      const int p = j * 256 + tid;      // 0..1023
      const int r = p >> 3, c = p & 7;
      const int cs = c ^ (r & 7);       // pre-swizzled global source
      gload_lds16(A + (arow0 + r) * Ki + k0 + cs * 8, (char*)As + p * 16);
      gload_lds16(Bt + (bcol0 + r) * Ki + k0 + cs * 8, (char*)Bs + p * 16);
    }
    __syncthreads();
#pragma unroll
    for (int kk = 0; kk < 2; ++kk) {
      short8 af[4], bfr[4];
#pragma unroll
      for (int i = 0; i < 4; ++i) {
        const int ar = wr * 64 + i * 16 + lrow;
        const int akg = kk * 4 + lkg;
        af[i] = *(const short8*)((const char*)As + ar * 128 + ((akg ^ (ar & 7)) << 4));
        const int br = wc * 64 + i * 16 + lrow;
        bfr[i] = *(const short8*)((const char*)Bs + br * 128 + ((akg ^ (br & 7)) << 4));
      }
#pragma unroll
      for (int i = 0; i < 4; ++i)
#pragma unroll
        for (int j = 0; j < 4; ++j)
          acc[i][j] = __builtin_amdgcn_mfma_f32_16x16x32_bf16(af[i], bfr[j], acc[i][j], 0, 0, 0);
    }
    __syncthreads();
  }
  const int crow = (lane >> 4) * 4;
  const int ccol = lane & 15;
#pragma unroll
  for (int i = 0; i < 4; ++i)
#pragma unroll
    for (int j = 0; j < 4; ++j)
#pragma unroll
      for (int rg = 0; rg < 4; ++rg) {
        const size_t grow = arow0 + wr * 64 + i * 16 + crow + rg;
        const size_t gcol = bcol0 + wc * 64 + j * 16 + ccol;
        float v = acc[i][j][rg];
        if (obf) {
          ((u16*)C)[grow * Ni + gcol] = f2b(v);
        } else {
          if (R) v += R[grow * Ni + gcol];
          ((float*)C)[grow * Ni + gcol] = v;
        }
      }
}

// ---------------- RoPE apply + (B,T,D)->(B,H,T,DH) transpose ----------------
__global__ __launch_bounds__(256) void rope_apply_kernel(const float* QKV, const float* COS, const float* SIN,
                                                         float* QRo, float* KRo, float* VRo) {
  int g = blockIdx.x;            // 2048
  int b = g >> 10, t = g & 1023;
  int j = threadIdx.x * 4;
  int h = j >> 6, jd = j & 63;
  const float* base = QKV + (size_t)g * 3072;
  f4 q = *(const f4*)(base + j);
  f4 k = *(const f4*)(base + 1024 + j);
  f4 v = *(const f4*)(base + 2048 + j);
  int pj = (jd < 32) ? j + 32 : j - 32;
  f4 qp = *(const f4*)(base + pj);
  f4 kp = *(const f4*)(base + 1024 + pj);
  float sgn = (jd < 32) ? -1.f : 1.f;
  f4 cv = *(const f4*)(COS + t * 64 + jd);
  f4 sv = *(const f4*)(SIN + t * 64 + jd);
  f4 qr = q * cv + (qp * sgn) * sv;
  f4 kr = k * cv + (kp * sgn) * sv;
  size_t o = ((size_t)(b * Hn + h) * Tn + t) * 64 + jd;
  *(f4*)(QRo + o) = qr; *(f4*)(KRo + o) = kr; *(f4*)(VRo + o) = v;
}

// ---------------- block-sparse attention (f32, online softmax) ----------------
__global__ __launch_bounds__(256) void attn_kernel(
    const float* __restrict__ QR, const float* __restrict__ KR, const float* __restrict__ VR,
    const int* __restrict__ sel, u16* __restrict__ O) {
  __shared__ float Qs[32][64], Ks[32][64], Vs[32][64], S[32][32];
  const int blk = blockIdx.x;    // 1024
  const int mq = blk & 31, h = (blk >> 5) & 15, b = blk >> 9;
  const int tid = threadIdx.x;
  const size_t bh = (size_t)(b * Hn + h) * Tn;
  {
    const f4* q4 = (const f4*)(QR + (bh + mq * 32) * 64);
    f4* s4 = (f4*)&Qs[0][0];
    s4[tid] = q4[tid]; s4[tid + 256] = q4[tid + 256];
  }
  const int row = tid >> 3, dg = tid & 7;
  const int dh0 = dg * 8;
  f4 acc0 = {0.f,0.f,0.f,0.f}, acc1 = {0.f,0.f,0.f,0.f};
  float m_i = -3e38f, l_i = 0.f;
  for (int mk = 0; mk <= mq; ++mk) {
    if (!(sel[b * 32 + mk] | (mk == mq))) continue;
    __syncthreads();   // prior-iter reads done; Qs visible on first iter
    {
      const f4* k4 = (const f4*)(KR + (bh + mk * 32) * 64);
      const f4* v4 = (const f4*)(VR + (bh + mk * 32) * 64);
      ((f4*)Ks)[tid] = k4[tid]; ((f4*)Ks)[tid + 256] = k4[tid + 256];
      ((f4*)Vs)[tid] = v4[tid]; ((f4*)Vs)[tid + 256] = v4[tid + 256];
    }
    __syncthreads();
#pragma unroll
    for (int c = 0; c < 4; ++c) {
      const int idx = tid * 4 + c;
      const int qi = idx >> 5, kj = idx & 31;
      const f4* qv = (const f4*)Qs[qi];
      const f4* kv = (const f4*)Ks[kj];
      f4 sv = {0.f,0.f,0.f,0.f};
#pragma unroll
      for (int d = 0; d < 16; ++d) sv += qv[d] * kv[d];
      float s = (sv[0] + sv[1] + sv[2] + sv[3]) * 0.125f;
      if (mk == mq && kj > qi) s = -3e38f;
      S[qi][kj] = s;
    }
    __syncthreads();
    float mx = m_i;
#pragma unroll
    for (int j2 = 0; j2 < 32; ++j2) mx = fmaxf(mx, S[row][j2]);
    const float resc = __expf(m_i - mx);
    float pv[4]; float psum = 0.f;
#pragma unroll
    for (int c = 0; c < 4; ++c) {
      pv[c] = __expf(S[row][dg * 4 + c] - mx);
      psum += pv[c];
    }
    __syncthreads();   // all raw-score reads done
#pragma unroll
    for (int c = 0; c < 4; ++c) S[row][dg * 4 + c] = pv[c];
    psum += __shfl_xor(psum, 1);
    psum += __shfl_xor(psum, 2);
    psum += __shfl_xor(psum, 4);
    l_i = l_i * resc + psum;
    m_i = mx;
    acc0 *= resc; acc1 *= resc;
    __syncthreads();   // p visible
#pragma unroll
    for (int kj = 0; kj < 32; ++kj) {
      const float p = S[row][kj];
      const f4* vv = (const f4*)&Vs[kj][dh0];
      acc0 += vv[0] * p; acc1 += vv[1] * p;
    }
  }
  const float inv = 1.f / l_i;
  us8 o;
#pragma unroll
  for (int e = 0; e < 4; ++e) { o[e] = f2b(acc0[e] * inv); o[4 + e] = f2b(acc1[e] * inv); }
  const int t = mq * 32 + row;
  *(us8*)(O + (size_t)(b * Tn + t) * Dn + h * 64 + dh0) = o;
}

// ---------------- silu(g1)*g3 (bf16 in, bf16 out) ----------------
__global__ __launch_bounds__(256) void silu_mul_b_kernel(const u16* G13b, u16* U) {
  int m = blockIdx.x;            // 2048
  const u16* g1 = G13b + (size_t)m * 8192;
  const u16* g3 = g1 + 4096;
  int tid = threadIdx.x;
#pragma unroll
  for (int c = 0; c < 2; ++c) {
    int i = tid + 256 * c;       // us8 index, 512 per half-row
    us8 a = ((const us8*)g1)[i];
    us8 bb = ((const us8*)g3)[i];
    us8 o;
#pragma unroll
    for (int e = 0; e < 8; ++e) {
      float av = b2f(a[e]), bv = b2f(bb[e]);
      float s = av / (1.f + __expf(-av));
      o[e] = f2b(s * bv);
    }
    ((us8*)(U + (size_t)m * 4096))[i] = o;
  }
}

extern "C" void kernel_launch(void* const* d_in, const int* in_sizes, int n_in,
                              void* d_out, int out_size, void* d_ws, size_t ws_size,
                              hipStream_t stream) {
  const int*   ids   = (const int*)d_in[0];
  const float* emb   = (const float*)d_in[1];
  const float* wq    = (const float*)d_in[2];
  const float* wk    = (const float*)d_in[3];
  const float* wv    = (const float*)d_in[4];
  const float* wo    = (const float*)d_in[5];
  const float* w1    = (const float*)d_in[6];
  const float* w2    = (const float*)d_in[7];
  const float* w3    = (const float*)d_in[8];
  const float* anrm  = (const float*)d_in[9];
  const float* fnrm  = (const float*)d_in[10];
  const float* finrm = (const float*)d_in[11];
  const float* lmw   = (const float*)d_in[12];
  float* out = (float*)d_out;

  char* ws = (char*)d_ws;
  size_t off = 0;
  auto alloc = [&](size_t sz) { void* p = ws + off; off += (sz + 255) & ~(size_t)255; return p; };
  const size_t MB = 1024ull * 1024ull;

  float* X    = (float*)alloc((size_t)GM * Dn * 4);      // 8 MiB
  u16*   Hb   = (u16*)alloc((size_t)GM * Dn * 2);        // 4 MiB
  float* COS  = (float*)alloc((size_t)Tn * 64 * 4);      // 256 KiB
  float* SIN  = (float*)alloc((size_t)Tn * 64 * 4);      // 256 KiB
  int*   SEL  = (int*)alloc(256);
  // per-layer converted weights (reused each layer): 32 MiB
  u16*   QKVl = (u16*)alloc((size_t)3072 * 1024 * 2);    // 6 MiB
  u16*   WOl  = (u16*)alloc((size_t)1024 * 1024 * 2);    // 2 MiB
  u16*   W13l = (u16*)alloc((size_t)8192 * 1024 * 2);    // 16 MiB
  u16*   W2l  = (u16*)alloc((size_t)1024 * 4096 * 2);    // 8 MiB
  char*  SCR  = (char*)alloc(66 * MB);                   // phase overlay

  if (off > ws_size) return;  // tripwire: absmax would be exactly 3.796875 (zero out)

  // quality-phase overlays on SCR
  float* Ac  = (float*)SCR;              // 1 MiB
  float* Bc  = (float*)(SCR + 1 * MB);   // 1 MiB
  float* RHO = (float*)(SCR + 2 * MB);   // 8 KiB
  // attention-phase overlays (52 MiB)
  float* QKVf = (float*)SCR;             // 24 MiB
  float* QRb  = (float*)(SCR + 24 * MB); // 8 MiB
  float* KRb  = (float*)(SCR + 32 * MB); // 8 MiB
  float* VRb  = (float*)(SCR + 40 * MB); // 8 MiB
  u16*   Ob   = (u16*)(SCR + 48 * MB);   // 4 MiB
  // ffn-phase overlays (48 MiB)
  u16*   G13b = (u16*)SCR;               // 32 MiB (bf16)
  u16*   Ub   = (u16*)(SCR + 32 * MB);   // 16 MiB
  // final-phase overlay (62.5 MiB)
  u16*   LMT  = (u16*)SCR;

  // ---- setup ----
  rope_tab_kernel<<<Tn, 64, 0, stream>>>(COS, SIN);
  embed_kernel<<<GM, 256, 0, stream>>>(ids, emb, X);
  qa_kernel<<<Bn * 128, 256, 0, stream>>>(X, Ac, Bc);
  qr_kernel<<<Bn * 256, 256, 0, stream>>>(Ac, Bc, X, RHO);
  topk_kernel<<<Bn, 32, 0, stream>>>(RHO, SEL);

  // ---- layers ----
  for (int l = 0; l < Ln; ++l) {
    const size_t dd = (size_t)1024 * 1024;
    const size_t df = (size_t)1024 * 4096;
    // convert this layer's weights: f32 (K,N) -> bf16 (N,K)
    transpose_to_bf16<<<dim3(32, 32), 256, 0, stream>>>(wq + l * dd, QKVl, 1024, 1024);
    transpose_to_bf16<<<dim3(32, 32), 256, 0, stream>>>(wk + l * dd, QKVl + dd, 1024, 1024);
    transpose_to_bf16<<<dim3(32, 32), 256, 0, stream>>>(wv + l * dd, QKVl + 2 * dd, 1024, 1024);
    transpose_to_bf16<<<dim3(32, 32), 256, 0, stream>>>(wo + l * dd, WOl, 1024, 1024);
    transpose_to_bf16<<<dim3(128, 32), 256, 0, stream>>>(w1 + l * df, W13l, 1024, 4096);
    transpose_to_bf16<<<dim3(128, 32), 256, 0, stream>>>(w3 + l * df, W13l + df, 1024, 4096);
    transpose_to_bf16<<<dim3(32, 128), 256, 0, stream>>>(w2 + l * df, W2l, 4096, 1024);

    rmsnorm_kernel<<<GM, 256, 0, stream>>>(X, anrm + l * Dn, Hb);
    gemm_bf16_kernel<<<dim3(24, 16), 256, 0, stream>>>(Hb, QKVl, QKVf, nullptr, 3072, 1024, 0);
    rope_apply_kernel<<<GM, 256, 0, stream>>>(QKVf, COS, SIN, QRb, KRb, VRb);
    attn_kernel<<<Bn * Hn * 32, 256, 0, stream>>>(QRb, KRb, VRb, SEL, Ob);
    gemm_bf16_kernel<<<dim3(8, 16), 256, 0, stream>>>(Ob, WOl, X, X, 1024, 1024, 0);
    rmsnorm_kernel<<<GM, 256, 0, stream>>>(X, fnrm + l * Dn, Hb);
    gemm_bf16_kernel<<<dim3(64, 16), 256, 0, stream>>>(Hb, W13l, G13b, nullptr, 8192, 1024, 1);
    silu_mul_b_kernel<<<GM, 256, 0, stream>>>(G13b, Ub);
    gemm_bf16_kernel<<<dim3(8, 16), 256, 0, stream>>>(Ub, W2l, X, X, 1024, 4096, 0);
  }

  // ---- final norm + lm_head ----
  transpose_to_bf16<<<dim3(1000, 32), 256, 0, stream>>>(lmw, LMT, 1024, Vn);
  rmsnorm_kernel<<<GM, 256, 0, stream>>>(X, finrm, Hb);
  gemm_bf16_kernel<<<dim3(250, 16), 256, 0, stream>>>(Hb, LMT, out, nullptr, Vn, 1024, 0);
}

// Round 4
// 1582.241 us; speedup vs baseline: 1.0088x; 1.0088x over previous
//
#include <hip/hip_runtime.h>
#include <hip/hip_bf16.h>

#define Bn 2
#define Tn 1024
#define Dn 1024
#define Hn 16
#define DHn 64
#define FFn 4096
#define Ln 2
#define Vn 32000
#define GM 2048   // B*T rows

typedef unsigned short u16;
typedef __attribute__((ext_vector_type(4))) float f4;
typedef __attribute__((ext_vector_type(4))) unsigned short us4;
typedef __attribute__((ext_vector_type(8))) unsigned short us8;
typedef __attribute__((ext_vector_type(8))) short short8;
typedef __attribute__((ext_vector_type(4))) float f32x4;

__device__ __forceinline__ u16 f2b(float x) {
  union { __hip_bfloat16 h; u16 u; } v; v.h = __float2bfloat16(x); return v.u;
}
__device__ __forceinline__ float b2f(u16 u) {
  union { unsigned int i; float f; } v; v.i = ((unsigned int)u) << 16; return v.f;
}
__device__ __forceinline__ float wred64(float v) {
#pragma unroll
  for (int m = 32; m > 0; m >>= 1) v += __shfl_xor(v, m);
  return v;
}
__device__ __forceinline__ void gload_lds16(const void* g, void* l) {
  __builtin_amdgcn_global_load_lds(
      (const __attribute__((address_space(1))) unsigned int*)g,
      (__attribute__((address_space(3))) unsigned int*)l, 16, 0, 0);
}

// ---------------- RoPE tables ----------------
__global__ void rope_tab_kernel(float* COS, float* SIN) {
  int t = blockIdx.x;            // 1024
  int j = threadIdx.x;           // 64
  float inv = __expf(-(float)(j & 31) * (9.210340371976184f / 32.f)); // 10000^{-i/32}
  float th = (float)t * inv;
  COS[t * 64 + j] = cosf(th);
  SIN[t * 64 + j] = sinf(th);
}

// ---------------- embedding gather ----------------
__global__ __launch_bounds__(256) void embed_kernel(const int* ids, const float* emb, float* x) {
  int g = blockIdx.x;            // 2048
  int id = ids[g];
  const f4* src = (const f4*)(emb + (size_t)id * Dn);
  f4* dst = (f4*)(x + (size_t)g * Dn);
  dst[threadIdx.x] = src[threadIdx.x];
}

// ---------------- quality: DFT coefficients A,B (f=0..127) ----------------
__global__ __launch_bounds__(256) void qa_kernel(const float* x, float* Ac, float* Bc) {
  __shared__ float ct[1024], st[1024];
  int blk = blockIdx.x;          // 256: b*128+f
  int b = blk >> 7, f = blk & 127;
  for (int t = threadIdx.x; t < 1024; t += 256) {
    float u = (float)((f * t) & 1023) * (6.283185307179586f / 1024.f);
    ct[t] = cosf(u); st[t] = sinf(u);
  }
  __syncthreads();
  int d0 = threadIdx.x * 4;
  f4 a = {0.f,0.f,0.f,0.f}, bb = {0.f,0.f,0.f,0.f};
  const float* xb = x + (size_t)b * Tn * Dn + d0;
  for (int t = 0; t < 1024; ++t) {
    f4 xv = *(const f4*)(xb + (size_t)t * Dn);
    float c = ct[t], s = st[t];
    a += xv * c; bb += xv * s;
  }
  size_t o = ((size_t)b * 128 + f) * Dn + d0;
  *(f4*)(Ac + o) = a; *(f4*)(Bc + o) = bb;
}

// ---------------- quality: rho per (b,t) (4 t per block) ----------------
__global__ __launch_bounds__(256) void qr_kernel(const float* Ac, const float* Bc,
                                                 const float* x, float* rho) {
  __shared__ float phc[128][4], phs[128][4];
  __shared__ float redN[4], redD[4];
  int blk = blockIdx.x;          // 512
  int b = blk >> 8, t0 = (blk & 255) * 4;
  int tid = threadIdx.x;
#pragma unroll
  for (int rep = 0; rep < 2; ++rep) {
    int e = rep * 256 + tid;     // 512 entries
    int f = e >> 2, tt = e & 3;
    float u = (float)((f * (t0 + tt)) & 1023) * (6.283185307179586f / 1024.f);
    phc[f][tt] = cosf(u); phs[f][tt] = sinf(u);
  }
  int d0 = tid * 4;
  const float* Ab = Ac + (size_t)b * 128 * Dn + d0;
  const float* Bb = Bc + (size_t)b * 128 * Dn + d0;
  f4 a0 = *(const f4*)Ab;
  float sacc[4][4];
#pragma unroll
  for (int tt = 0; tt < 4; ++tt)
#pragma unroll
    for (int c = 0; c < 4; ++c) sacc[tt][c] = 0.5f * a0[c];
  __syncthreads();
  for (int f = 1; f < 128; ++f) {
    f4 a = *(const f4*)(Ab + (size_t)f * Dn);
    f4 bb = *(const f4*)(Bb + (size_t)f * Dn);
#pragma unroll
    for (int tt = 0; tt < 4; ++tt) {
      float c = phc[f][tt], s = phs[f][tt];
#pragma unroll
      for (int e = 0; e < 4; ++e) sacc[tt][e] += a[e] * c + bb[e] * s;
    }
  }
  int wave = tid >> 6, lane = tid & 63;
  for (int tt = 0; tt < 4; ++tt) {
    f4 xv = *(const f4*)(x + ((size_t)b * Tn + t0 + tt) * Dn + d0);
    float num = 0.f, den = 0.f;
#pragma unroll
    for (int e = 0; e < 4; ++e) {
      float hl = sacc[tt][e] * (2.f / 1024.f);
      num += hl * hl;
      den += xv[e] * xv[e];
    }
    float rn = wred64(num), rd = wred64(den);
    if (lane == 0) { redN[wave] = rn; redD[wave] = rd; }
    __syncthreads();
    if (tid == 0) {
      float n = redN[0] + redN[1] + redN[2] + redN[3];
      float dd = redD[0] + redD[1] + redD[2] + redD[3];
      rho[(size_t)b * Tn + t0 + tt] = n / (dd + 1e-6f);
    }
    __syncthreads();
  }
}

// ---------------- block quality mean + top-8 ----------------
__global__ void topk_kernel(const float* rho, int* sel) {
  __shared__ float bq[32];
  __shared__ int chosen[32];
  int b = blockIdx.x;            // 2
  int m = threadIdx.x;           // 32
  float s = 0.f;
  for (int j = 0; j < 32; ++j) s += rho[(size_t)b * Tn + m * 32 + j];
  bq[m] = s * (1.f / 32.f); chosen[m] = 0;
  __syncthreads();
  if (m == 0) {
    for (int it = 0; it < 8; ++it) {
      float best = -3e38f; int bi = 0;
      for (int mm = 0; mm < 32; ++mm) if (bq[mm] > best) { best = bq[mm]; bi = mm; }
      chosen[bi] = 1; bq[bi] = -3e38f;
    }
  }
  __syncthreads();
  sel[b * 32 + m] = chosen[m];
}

// ---------------- f32 (K,N) -> bf16 (N,K) transpose, 64x64 tiles ----------------
// dst row = (n>>4)*rowmul + rowadd + (n&15). Plain: rowmul=16,rowadd=0 -> row n.
// W1/W3 interleave: rowmul=32, rowadd 0/16.
__global__ __launch_bounds__(256) void transpose64(const float* __restrict__ src, u16* __restrict__ dst,
                                                   int K, int N, int rowmul, int rowadd) {
  __shared__ u16 tile[64][72];
  const int n0 = blockIdx.x * 64, k0 = blockIdx.y * 64;
  const int tid = threadIdx.x;
  const int r = tid >> 2;            // 0..63
  const int c0 = (tid & 3) * 16;
  const float* s = src + (size_t)(k0 + r) * N + n0 + c0;
#pragma unroll
  for (int q = 0; q < 4; ++q) {
    f4 v = *(const f4*)(s + q * 4);
#pragma unroll
    for (int e = 0; e < 4; ++e) tile[c0 + q * 4 + e][r] = f2b(v[e]);
  }
  __syncthreads();
  const int n = n0 + r;
  const size_t drow = (size_t)((n >> 4) * rowmul + rowadd + (n & 15));
  us8* d = (us8*)(dst + drow * K + k0 + c0);
  us8 o0, o1;
#pragma unroll
  for (int e = 0; e < 8; ++e) { o0[e] = tile[r][c0 + e]; o1[e] = tile[r][c0 + 8 + e]; }
  d[0] = o0; d[1] = o1;
}

// ---------------- RMSNorm (f32 in, bf16 out) ----------------
__global__ __launch_bounds__(256) void rmsnorm_kernel(const float* x, const float* w, u16* out) {
  __shared__ float red[4];
  int g = blockIdx.x;            // 2048
  int tid = threadIdx.x;
  f4 xv = ((const f4*)(x + (size_t)g * Dn))[tid];
  float ss = xv[0]*xv[0] + xv[1]*xv[1] + xv[2]*xv[2] + xv[3]*xv[3];
  ss = wred64(ss);
  if ((tid & 63) == 0) red[tid >> 6] = ss;
  __syncthreads();
  float tot = red[0] + red[1] + red[2] + red[3];
  float r = rsqrtf(tot * (1.f / 1024.f) + 1e-6f);
  f4 wv = ((const f4*)w)[tid];
  us4 o;
#pragma unroll
  for (int e = 0; e < 4; ++e) o[e] = f2b(xv[e] * r * wv[e]);
  *(us4*)(out + (size_t)g * Dn + tid * 4) = o;
}

// ---------------- bf16 MFMA GEMM: C(2048,Ni) = A(2048,Ki) * Bt(Ni,Ki)^T ----------------
// 1-D grid, XCD-chunk swizzle. cf=0: row-fastest within chunk; cf=1: col-fastest.
// EPI 0: f32 C (+R);  EPI 2: rope->QR/KR/VR;  EPI 3: silu(w1)*w3 -> bf16 U (Ni=8192 interleaved).
template<int EPI>
__global__ __launch_bounds__(256) void gemm_bf16(
    const u16* __restrict__ A, const u16* __restrict__ Bt,
    float* C, const float* R, u16* U,
    float* QRo, float* KRo, float* VRo, const float* __restrict__ COS, const float* __restrict__ SIN,
    int Ni, int Ki, int cf) {
  __shared__ short8 As[1024];    // 128 rows x 64 k (bf16), 16KB
  __shared__ short8 Bs[1024];
  const int tid = threadIdx.x;
  const int wave = tid >> 6, lane = tid & 63;
  const int wr = wave >> 1, wc = wave & 1;
  const int lrow = lane & 15, lkg = lane >> 4;
  // swizzle: contiguous logical range per XCD
  const int lg = (blockIdx.x & 7) * ((int)gridDim.x >> 3) + ((int)blockIdx.x >> 3);
  int bx, by;
  if (cf) { const int nbx = Ni >> 7; bx = lg % nbx; by = lg / nbx; }
  else    { by = lg & 15; bx = lg >> 4; }
  const size_t arow0 = (size_t)by * 128;
  const size_t bcol0 = (size_t)bx * 128;
  const f32x4 zero4 = {0.f, 0.f, 0.f, 0.f};
  f32x4 acc[4][4];
#pragma unroll
  for (int i = 0; i < 4; ++i)
#pragma unroll
    for (int j = 0; j < 4; ++j) acc[i][j] = zero4;
  const int nK = Ki >> 6;
  for (int kb = 0; kb < nK; ++kb) {
    const size_t k0 = (size_t)kb << 6;
#pragma unroll
    for (int j = 0; j < 4; ++j) {
      const int p = j * 256 + tid;      // 0..1023
      const int r = p >> 3, c = p & 7;
      const int cs = c ^ (r & 7);       // pre-swizzled global source
      gload_lds16(A + (arow0 + r) * Ki + k0 + cs * 8, (char*)As + p * 16);
      gload_lds16(Bt + (bcol0 + r) * Ki + k0 + cs * 8, (char*)Bs + p * 16);
    }
    __syncthreads();
#pragma unroll
    for (int kk = 0; kk < 2; ++kk) {
      short8 af[4], bfr[4];
#pragma unroll
      for (int i = 0; i < 4; ++i) {
        const int ar = wr * 64 + i * 16 + lrow;
        const int akg = kk * 4 + lkg;
        af[i] = *(const short8*)((const char*)As + ar * 128 + ((akg ^ (ar & 7)) << 4));
        const int br = wc * 64 + i * 16 + lrow;
        bfr[i] = *(const short8*)((const char*)Bs + br * 128 + ((akg ^ (br & 7)) << 4));
      }
#pragma unroll
      for (int i = 0; i < 4; ++i)
#pragma unroll
        for (int j = 0; j < 4; ++j)
          acc[i][j] = __builtin_amdgcn_mfma_f32_16x16x32_bf16(af[i], bfr[j], acc[i][j], 0, 0, 0);
    }
    __syncthreads();
  }
  const int crow = (lane >> 4) * 4;
  const int ccol = lane & 15;
  if (EPI == 0) {
#pragma unroll
    for (int i = 0; i < 4; ++i)
#pragma unroll
      for (int j = 0; j < 4; ++j)
#pragma unroll
        for (int rg = 0; rg < 4; ++rg) {
          const size_t grow = arow0 + wr * 64 + i * 16 + crow + rg;
          const size_t gcol = bcol0 + wc * 64 + j * 16 + ccol;
          float v = acc[i][j][rg];
          if (R) v += R[grow * Ni + gcol];
          C[grow * Ni + gcol] = v;
        }
  } else if (EPI == 2) {
    const int sec = (int)(bcol0 >> 10);                       // 0=q,1=k,2=v
    const int hh = (((int)bcol0 & 1023) >> 6) + wc;           // head 0..15
    float* dstQK = (sec == 0) ? QRo : KRo;
#pragma unroll
    for (int i = 0; i < 4; ++i)
#pragma unroll
      for (int rg = 0; rg < 4; ++rg) {
        const int t = (int)arow0 + wr * 64 + i * 16 + crow + rg;
        const int bb = t >> 10, tt = t & 1023;
        const size_t obase = ((size_t)(bb * Hn + hh) * Tn + tt) * 64;
#pragma unroll
        for (int j = 0; j < 4; ++j) {
          const int jd = j * 16 + ccol;
          const float v = acc[i][j][rg];
          if (sec < 2) {
            const float p = acc[i][j ^ 2][rg];
            const float cs = COS[tt * 64 + jd], sn = SIN[tt * 64 + jd];
            dstQK[obase + jd] = v * cs + ((j < 2) ? -p : p) * sn;
          } else {
            VRo[obase + jd] = v;
          }
        }
      }
  } else if (EPI == 3) {
#pragma unroll
    for (int i = 0; i < 4; ++i)
#pragma unroll
      for (int rg = 0; rg < 4; ++rg) {
        const size_t grow = arow0 + wr * 64 + i * 16 + crow + rg;
#pragma unroll
        for (int jp = 0; jp < 2; ++jp) {
          const int j = jp * 2;
          const float a = acc[i][j][rg];
          const float g3 = acc[i][j + 1][rg];
          const float s = (a / (1.f + __expf(-a))) * g3;
          const int f = ((((int)bcol0 + wc * 64 + j * 16) >> 5) << 4) + ccol;
          U[grow * 4096 + f] = f2b(s);
        }
      }
  }
}

// ---------------- block-sparse attention (f32, online softmax) ----------------
__global__ __launch_bounds__(256) void attn_kernel(
    const float* __restrict__ QR, const float* __restrict__ KR, const float* __restrict__ VR,
    const int* __restrict__ sel, u16* __restrict__ O) {
  __shared__ float Qs[32][64], Ks[32][64], Vs[32][64], S[32][32];
  const int blk = blockIdx.x;    // 1024
  const int mq = blk & 31, h = (blk >> 5) & 15, b = blk >> 9;
  const int tid = threadIdx.x;
  const size_t bh = (size_t)(b * Hn + h) * Tn;
  {
    const f4* q4 = (const f4*)(QR + (bh + mq * 32) * 64);
    f4* s4 = (f4*)&Qs[0][0];
    s4[tid] = q4[tid]; s4[tid + 256] = q4[tid + 256];
  }
  const int row = tid >> 3, dg = tid & 7;
  const int dh0 = dg * 8;
  f4 acc0 = {0.f,0.f,0.f,0.f}, acc1 = {0.f,0.f,0.f,0.f};
  float m_i = -3e38f, l_i = 0.f;
  for (int mk = 0; mk <= mq; ++mk) {
    if (!(sel[b * 32 + mk] | (mk == mq))) continue;
    __syncthreads();   // prior-iter reads done; Qs visible on first iter
    {
      const f4* k4 = (const f4*)(KR + (bh + mk * 32) * 64);
      const f4* v4 = (const f4*)(VR + (bh + mk * 32) * 64);
      ((f4*)Ks)[tid] = k4[tid]; ((f4*)Ks)[tid + 256] = k4[tid + 256];
      ((f4*)Vs)[tid] = v4[tid]; ((f4*)Vs)[tid + 256] = v4[tid + 256];
    }
    __syncthreads();
#pragma unroll
    for (int c = 0; c < 4; ++c) {
      const int idx = tid * 4 + c;
      const int qi = idx >> 5, kj = idx & 31;
      const f4* qv = (const f4*)Qs[qi];
      const f4* kv = (const f4*)Ks[kj];
      f4 sv = {0.f,0.f,0.f,0.f};
#pragma unroll
      for (int d = 0; d < 16; ++d) sv += qv[d] * kv[d];
      float s = (sv[0] + sv[1] + sv[2] + sv[3]) * 0.125f;
      if (mk == mq && kj > qi) s = -3e38f;
      S[qi][kj] = s;
    }
    __syncthreads();
    float mx = m_i;
#pragma unroll
    for (int j2 = 0; j2 < 32; ++j2) mx = fmaxf(mx, S[row][j2]);
    const float resc = __expf(m_i - mx);
    float pv[4]; float psum = 0.f;
#pragma unroll
    for (int c = 0; c < 4; ++c) {
      pv[c] = __expf(S[row][dg * 4 + c] - mx);
      psum += pv[c];
    }
    __syncthreads();   // all raw-score reads done
#pragma unroll
    for (int c = 0; c < 4; ++c) S[row][dg * 4 + c] = pv[c];
    psum += __shfl_xor(psum, 1);
    psum += __shfl_xor(psum, 2);
    psum += __shfl_xor(psum, 4);
    l_i = l_i * resc + psum;
    m_i = mx;
    acc0 *= resc; acc1 *= resc;
    __syncthreads();   // p visible
#pragma unroll
    for (int kj = 0; kj < 32; ++kj) {
      const float p = S[row][kj];
      const f4* vv = (const f4*)&Vs[kj][dh0];
      acc0 += vv[0] * p; acc1 += vv[1] * p;
    }
  }
  const float inv = 1.f / l_i;
  us8 o;
#pragma unroll
  for (int e = 0; e < 4; ++e) { o[e] = f2b(acc0[e] * inv); o[4 + e] = f2b(acc1[e] * inv); }
  const int t = mq * 32 + row;
  *(us8*)(O + (size_t)(b * Tn + t) * Dn + h * 64 + dh0) = o;
}

extern "C" void kernel_launch(void* const* d_in, const int* in_sizes, int n_in,
                              void* d_out, int out_size, void* d_ws, size_t ws_size,
                              hipStream_t stream) {
  const int*   ids   = (const int*)d_in[0];
  const float* emb   = (const float*)d_in[1];
  const float* wq    = (const float*)d_in[2];
  const float* wk    = (const float*)d_in[3];
  const float* wv    = (const float*)d_in[4];
  const float* wo    = (const float*)d_in[5];
  const float* w1    = (const float*)d_in[6];
  const float* w2    = (const float*)d_in[7];
  const float* w3    = (const float*)d_in[8];
  const float* anrm  = (const float*)d_in[9];
  const float* fnrm  = (const float*)d_in[10];
  const float* finrm = (const float*)d_in[11];
  const float* lmw   = (const float*)d_in[12];
  float* out = (float*)d_out;

  char* ws = (char*)d_ws;
  size_t off = 0;
  auto alloc = [&](size_t sz) { void* p = ws + off; off += (sz + 255) & ~(size_t)255; return p; };
  const size_t MB = 1024ull * 1024ull;

  float* X    = (float*)alloc((size_t)GM * Dn * 4);      // 8 MiB
  u16*   Hb   = (u16*)alloc((size_t)GM * Dn * 2);        // 4 MiB
  float* COS  = (float*)alloc((size_t)Tn * 64 * 4);      // 256 KiB
  float* SIN  = (float*)alloc((size_t)Tn * 64 * 4);      // 256 KiB
  int*   SEL  = (int*)alloc(256);
  // per-layer converted weights (reused each layer): 32 MiB
  u16*   QKVl = (u16*)alloc((size_t)3072 * 1024 * 2);    // 6 MiB
  u16*   WOl  = (u16*)alloc((size_t)1024 * 1024 * 2);    // 2 MiB
  u16*   W13l = (u16*)alloc((size_t)8192 * 1024 * 2);    // 16 MiB (w1/w3 16-col interleaved)
  u16*   W2l  = (u16*)alloc((size_t)1024 * 4096 * 2);    // 8 MiB
  char*  SCR  = (char*)alloc(66 * MB);                   // phase overlay

  if (off > ws_size) return;  // tripwire: absmax would be exactly 3.796875 (zero out)

  // quality-phase overlays on SCR
  float* Ac  = (float*)SCR;              // 1 MiB
  float* Bc  = (float*)(SCR + 1 * MB);   // 1 MiB
  float* RHO = (float*)(SCR + 2 * MB);   // 8 KiB
  // attention-phase overlays
  float* QRb  = (float*)(SCR + 24 * MB); // 8 MiB
  float* KRb  = (float*)(SCR + 32 * MB); // 8 MiB
  float* VRb  = (float*)(SCR + 40 * MB); // 8 MiB
  u16*   Ob   = (u16*)(SCR + 48 * MB);   // 4 MiB
  // ffn-phase overlay
  u16*   Ub   = (u16*)(SCR + 0 * MB);    // 16 MiB (silu(g1)*g3, bf16)
  // final-phase overlay (62.5 MiB)
  u16*   LMT  = (u16*)SCR;

  // ---- setup ----
  rope_tab_kernel<<<Tn, 64, 0, stream>>>(COS, SIN);
  embed_kernel<<<GM, 256, 0, stream>>>(ids, emb, X);
  qa_kernel<<<Bn * 128, 256, 0, stream>>>(X, Ac, Bc);
  qr_kernel<<<Bn * 256, 256, 0, stream>>>(Ac, Bc, X, RHO);
  topk_kernel<<<Bn, 32, 0, stream>>>(RHO, SEL);

  // ---- layers ----
  for (int l = 0; l < Ln; ++l) {
    const size_t dd = (size_t)1024 * 1024;
    const size_t df = (size_t)1024 * 4096;
    // convert this layer's weights: f32 (K,N) -> bf16 (N,K)
    transpose64<<<dim3(16, 16), 256, 0, stream>>>(wq + l * dd, QKVl, 1024, 1024, 16, 0);
    transpose64<<<dim3(16, 16), 256, 0, stream>>>(wk + l * dd, QKVl + dd, 1024, 1024, 16, 0);
    transpose64<<<dim3(16, 16), 256, 0, stream>>>(wv + l * dd, QKVl + 2 * dd, 1024, 1024, 16, 0);
    transpose64<<<dim3(16, 16), 256, 0, stream>>>(wo + l * dd, WOl, 1024, 1024, 16, 0);
    transpose64<<<dim3(64, 16), 256, 0, stream>>>(w1 + l * df, W13l, 1024, 4096, 32, 0);
    transpose64<<<dim3(64, 16), 256, 0, stream>>>(w3 + l * df, W13l, 1024, 4096, 32, 16);
    transpose64<<<dim3(16, 64), 256, 0, stream>>>(w2 + l * df, W2l, 4096, 1024, 16, 0);

    rmsnorm_kernel<<<GM, 256, 0, stream>>>(X, anrm + l * Dn, Hb);
    // QKV + fused RoPE + head-split
    gemm_bf16<2><<<384, 256, 0, stream>>>(Hb, QKVl, nullptr, nullptr, nullptr,
                                          QRb, KRb, VRb, COS, SIN, 3072, 1024, 0);
    attn_kernel<<<Bn * Hn * 32, 256, 0, stream>>>(QRb, KRb, VRb, SEL, Ob);
    gemm_bf16<0><<<128, 256, 0, stream>>>(Ob, WOl, X, X, nullptr,
                                          nullptr, nullptr, nullptr, nullptr, nullptr, 1024, 1024, 1);
    rmsnorm_kernel<<<GM, 256, 0, stream>>>(X, fnrm + l * Dn, Hb);
    // W1/W3 + fused silu*mul -> Ub (bf16)
    gemm_bf16<3><<<1024, 256, 0, stream>>>(Hb, W13l, nullptr, nullptr, Ub,
                                           nullptr, nullptr, nullptr, nullptr, nullptr, 8192, 1024, 0);
    gemm_bf16<0><<<128, 256, 0, stream>>>(Ub, W2l, X, X, nullptr,
                                          nullptr, nullptr, nullptr, nullptr, nullptr, 1024, 4096, 1);
  }

  // ---- final norm + lm_head ----
  transpose64<<<dim3(500, 16), 256, 0, stream>>>(lmw, LMT, 1024, Vn, 16, 0);
  rmsnorm_kernel<<<GM, 256, 0, stream>>>(X, finrm, Hb);
  gemm_bf16<0><<<4000, 256, 0, stream>>>(Hb, LMT, out, nullptr, nullptr,
                                         nullptr, nullptr, nullptr, nullptr, nullptr, Vn, 1024, 0);
}

// Round 5
// 1498.568 us; speedup vs baseline: 1.0652x; 1.0558x over previous
//
#include <hip/hip_runtime.h>
#include <hip/hip_bf16.h>

#define Bn 2
#define Tn 1024
#define Dn 1024
#define Hn 16
#define DHn 64
#define FFn 4096
#define Ln 2
#define Vn 32000
#define GM 2048   // B*T rows

typedef unsigned short u16;
typedef __attribute__((ext_vector_type(4))) float f4;
typedef __attribute__((ext_vector_type(4))) unsigned short us4;
typedef __attribute__((ext_vector_type(8))) unsigned short us8;
typedef __attribute__((ext_vector_type(8))) short short8;
typedef __attribute__((ext_vector_type(4))) float f32x4;

__device__ __forceinline__ u16 f2b(float x) {
  union { __hip_bfloat16 h; u16 u; } v; v.h = __float2bfloat16(x); return v.u;
}
__device__ __forceinline__ float b2f(u16 u) {
  union { unsigned int i; float f; } v; v.i = ((unsigned int)u) << 16; return v.f;
}
__device__ __forceinline__ float wred64(float v) {
#pragma unroll
  for (int m = 32; m > 0; m >>= 1) v += __shfl_xor(v, m);
  return v;
}
__device__ __forceinline__ void gload_lds16(const void* g, void* l) {
  __builtin_amdgcn_global_load_lds(
      (const __attribute__((address_space(1))) unsigned int*)g,
      (__attribute__((address_space(3))) unsigned int*)l, 16, 0, 0);
}

// ---------------- RoPE tables ----------------
__global__ void rope_tab_kernel(float* COS, float* SIN) {
  int t = blockIdx.x;            // 1024
  int j = threadIdx.x;           // 64
  float inv = __expf(-(float)(j & 31) * (9.210340371976184f / 32.f)); // 10000^{-i/32}
  float th = (float)t * inv;
  COS[t * 64 + j] = cosf(th);
  SIN[t * 64 + j] = sinf(th);
}

// ---------------- embedding gather ----------------
__global__ __launch_bounds__(256) void embed_kernel(const int* ids, const float* emb, float* x) {
  int g = blockIdx.x;            // 2048
  int id = ids[g];
  const f4* src = (const f4*)(emb + (size_t)id * Dn);
  f4* dst = (f4*)(x + (size_t)g * Dn);
  dst[threadIdx.x] = src[threadIdx.x];
}

// ---------------- quality: partial DFT coefficients, 8-way t-split ----------------
// grid 2048: b*1024 + f*8 + tc. Each handles 128 t's.
__global__ __launch_bounds__(256) void qa_kernel(const float* __restrict__ x,
                                                 float* __restrict__ PA, float* __restrict__ PB) {
  __shared__ float ct[128], st[128];
  int blk = blockIdx.x;
  int tc = blk & 7, f = (blk >> 3) & 127, b = blk >> 10;
  int t0 = tc * 128;
  if (threadIdx.x < 128) {
    int t = t0 + threadIdx.x;
    float u = (float)((f * t) & 1023) * (6.283185307179586f / 1024.f);
    ct[threadIdx.x] = cosf(u); st[threadIdx.x] = sinf(u);
  }
  __syncthreads();
  int d0 = threadIdx.x * 4;
  f4 a = {0.f,0.f,0.f,0.f}, bb = {0.f,0.f,0.f,0.f};
  const float* xb = x + ((size_t)b * Tn + t0) * Dn + d0;
  for (int t = 0; t < 128; ++t) {
    f4 xv = *(const f4*)(xb + (size_t)t * Dn);
    float c = ct[t], s = st[t];
    a += xv * c; bb += xv * s;
  }
  size_t o = (((size_t)b * 128 + f) * 8 + tc) * Dn + d0;
  *(f4*)(PA + o) = a; *(f4*)(PB + o) = bb;
}

// reduce 8 partials -> Ac, Bc. grid 256 = b*128+f
__global__ __launch_bounds__(256) void qa_red_kernel(const float* __restrict__ PA, const float* __restrict__ PB,
                                                     float* __restrict__ Ac, float* __restrict__ Bc) {
  int blk = blockIdx.x;
  int d0 = threadIdx.x * 4;
  const float* pa = PA + ((size_t)blk * 8) * Dn + d0;
  const float* pb = PB + ((size_t)blk * 8) * Dn + d0;
  f4 a = {0.f,0.f,0.f,0.f}, bb = {0.f,0.f,0.f,0.f};
#pragma unroll
  for (int tc = 0; tc < 8; ++tc) {
    a += *(const f4*)(pa + (size_t)tc * Dn);
    bb += *(const f4*)(pb + (size_t)tc * Dn);
  }
  *(f4*)(Ac + (size_t)blk * Dn + d0) = a;
  *(f4*)(Bc + (size_t)blk * Dn + d0) = bb;
}

// ---------------- quality: rho per (b,t) (4 t per block) ----------------
__global__ __launch_bounds__(256) void qr_kernel(const float* Ac, const float* Bc,
                                                 const float* x, float* rho) {
  __shared__ float phc[128][4], phs[128][4];
  __shared__ float redN[4], redD[4];
  int blk = blockIdx.x;          // 512
  int b = blk >> 8, t0 = (blk & 255) * 4;
  int tid = threadIdx.x;
#pragma unroll
  for (int rep = 0; rep < 2; ++rep) {
    int e = rep * 256 + tid;     // 512 entries
    int f = e >> 2, tt = e & 3;
    float u = (float)((f * (t0 + tt)) & 1023) * (6.283185307179586f / 1024.f);
    phc[f][tt] = cosf(u); phs[f][tt] = sinf(u);
  }
  int d0 = tid * 4;
  const float* Ab = Ac + (size_t)b * 128 * Dn + d0;
  const float* Bb = Bc + (size_t)b * 128 * Dn + d0;
  f4 a0 = *(const f4*)Ab;
  float sacc[4][4];
#pragma unroll
  for (int tt = 0; tt < 4; ++tt)
#pragma unroll
    for (int c = 0; c < 4; ++c) sacc[tt][c] = 0.5f * a0[c];
  __syncthreads();
  for (int f = 1; f < 128; ++f) {
    f4 a = *(const f4*)(Ab + (size_t)f * Dn);
    f4 bb = *(const f4*)(Bb + (size_t)f * Dn);
#pragma unroll
    for (int tt = 0; tt < 4; ++tt) {
      float c = phc[f][tt], s = phs[f][tt];
#pragma unroll
      for (int e = 0; e < 4; ++e) sacc[tt][e] += a[e] * c + bb[e] * s;
    }
  }
  int wave = tid >> 6, lane = tid & 63;
  for (int tt = 0; tt < 4; ++tt) {
    f4 xv = *(const f4*)(x + ((size_t)b * Tn + t0 + tt) * Dn + d0);
    float num = 0.f, den = 0.f;
#pragma unroll
    for (int e = 0; e < 4; ++e) {
      float hl = sacc[tt][e] * (2.f / 1024.f);
      num += hl * hl;
      den += xv[e] * xv[e];
    }
    float rn = wred64(num), rd = wred64(den);
    if (lane == 0) { redN[wave] = rn; redD[wave] = rd; }
    __syncthreads();
    if (tid == 0) {
      float n = redN[0] + redN[1] + redN[2] + redN[3];
      float dd = redD[0] + redD[1] + redD[2] + redD[3];
      rho[(size_t)b * Tn + t0 + tt] = n / (dd + 1e-6f);
    }
    __syncthreads();
  }
}

// ---------------- block quality mean + top-8 ----------------
__global__ void topk_kernel(const float* rho, int* sel) {
  __shared__ float bq[32];
  __shared__ int chosen[32];
  int b = blockIdx.x;            // 2
  int m = threadIdx.x;           // 32
  float s = 0.f;
  for (int j = 0; j < 32; ++j) s += rho[(size_t)b * Tn + m * 32 + j];
  bq[m] = s * (1.f / 32.f); chosen[m] = 0;
  __syncthreads();
  if (m == 0) {
    for (int it = 0; it < 8; ++it) {
      float best = -3e38f; int bi = 0;
      for (int mm = 0; mm < 32; ++mm) if (bq[mm] > best) { best = bq[mm]; bi = mm; }
      chosen[bi] = 1; bq[bi] = -3e38f;
    }
  }
  __syncthreads();
  sel[b * 32 + m] = chosen[m];
}

// ---------------- f32 (K,N) -> bf16 (N,K) transpose, 64x64 tiles ----------------
__global__ __launch_bounds__(256) void transpose64(const float* __restrict__ src, u16* __restrict__ dst,
                                                   int K, int N, int rowmul, int rowadd) {
  __shared__ u16 tile[64][72];
  const int n0 = blockIdx.x * 64, k0 = blockIdx.y * 64;
  const int tid = threadIdx.x;
  const int r = tid >> 2;            // 0..63
  const int c0 = (tid & 3) * 16;
  const float* s = src + (size_t)(k0 + r) * N + n0 + c0;
#pragma unroll
  for (int q = 0; q < 4; ++q) {
    f4 v = *(const f4*)(s + q * 4);
#pragma unroll
    for (int e = 0; e < 4; ++e) tile[c0 + q * 4 + e][r] = f2b(v[e]);
  }
  __syncthreads();
  const int n = n0 + r;
  const size_t drow = (size_t)((n >> 4) * rowmul + rowadd + (n & 15));
  us8* d = (us8*)(dst + drow * K + k0 + c0);
  us8 o0, o1;
#pragma unroll
  for (int e = 0; e < 8; ++e) { o0[e] = tile[r][c0 + e]; o1[e] = tile[r][c0 + 8 + e]; }
  d[0] = o0; d[1] = o1;
}

// ---------------- RMSNorm (f32 in, bf16 out) ----------------
__global__ __launch_bounds__(256) void rmsnorm_kernel(const float* x, const float* w, u16* out) {
  __shared__ float red[4];
  int g = blockIdx.x;            // 2048
  int tid = threadIdx.x;
  f4 xv = ((const f4*)(x + (size_t)g * Dn))[tid];
  float ss = xv[0]*xv[0] + xv[1]*xv[1] + xv[2]*xv[2] + xv[3]*xv[3];
  ss = wred64(ss);
  if ((tid & 63) == 0) red[tid >> 6] = ss;
  __syncthreads();
  float tot = red[0] + red[1] + red[2] + red[3];
  float r = rsqrtf(tot * (1.f / 1024.f) + 1e-6f);
  f4 wv = ((const f4*)w)[tid];
  us4 o;
#pragma unroll
  for (int e = 0; e < 4; ++e) o[e] = f2b(xv[e] * r * wv[e]);
  *(us4*)(out + (size_t)g * Dn + tid * 4) = o;
}

// ---------------- bf16 MFMA GEMM, double-buffered 2-phase ----------------
// C(2048,Ni) = A(2048,Ki) * Bt(Ni,Ki)^T. 1-D grid, XCD-chunk swizzle.
// EPI 0: f32 C (+R, or nontemporal if R==null);  EPI 2: rope->QR/KR/VR;  EPI 3: silu*mul -> bf16 U.
template<int EPI>
__global__ __launch_bounds__(256) void gemm_bf16(
    const u16* __restrict__ A, const u16* __restrict__ Bt,
    float* C, const float* R, u16* U,
    float* QRo, float* KRo, float* VRo, const float* __restrict__ COS, const float* __restrict__ SIN,
    int Ni, int Ki, int cf) {
  __shared__ short8 As[2][1024];    // 2 x 16KB
  __shared__ short8 Bs[2][1024];
  const int tid = threadIdx.x;
  const int wave = tid >> 6, lane = tid & 63;
  const int wr = wave >> 1, wc = wave & 1;
  const int lrow = lane & 15, lkg = lane >> 4;
  const int lg = (blockIdx.x & 7) * ((int)gridDim.x >> 3) + ((int)blockIdx.x >> 3);
  int bx, by;
  if (cf) { const int nbx = Ni >> 7; bx = lg % nbx; by = lg / nbx; }
  else    { by = lg & 15; bx = lg >> 4; }
  const size_t arow0 = (size_t)by * 128;
  const size_t bcol0 = (size_t)bx * 128;
  // staging addresses (constant per thread across K except k0)
  const int p0 = tid * 4;  // 4 consecutive p per thread? no: p = j*256+tid
  (void)p0;
  const f32x4 zero4 = {0.f, 0.f, 0.f, 0.f};
  f32x4 acc[4][4];
#pragma unroll
  for (int i = 0; i < 4; ++i)
#pragma unroll
    for (int j = 0; j < 4; ++j) acc[i][j] = zero4;
  const int nK = Ki >> 6;

  auto STAGE = [&](int buf, int kb) {
    const size_t k0 = (size_t)kb << 6;
#pragma unroll
    for (int j = 0; j < 4; ++j) {
      const int p = j * 256 + tid;      // 0..1023
      const int r = p >> 3, c = p & 7;
      const int cs = c ^ (r & 7);       // pre-swizzled global source
      gload_lds16(A + (arow0 + r) * Ki + k0 + cs * 8, (char*)&As[buf][0] + p * 16);
      gload_lds16(Bt + (bcol0 + r) * Ki + k0 + cs * 8, (char*)&Bs[buf][0] + p * 16);
    }
  };

  STAGE(0, 0);
  __syncthreads();            // drains vmcnt before barrier (compiler-emitted)
  int cur = 0;
  for (int kb = 0; kb < nK; ++kb) {
    if (kb + 1 < nK) STAGE(cur ^ 1, kb + 1);   // async prefetch into other buffer
#pragma unroll
    for (int kk = 0; kk < 2; ++kk) {
      short8 af[4], bfr[4];
#pragma unroll
      for (int i = 0; i < 4; ++i) {
        const int ar = wr * 64 + i * 16 + lrow;
        const int akg = kk * 4 + lkg;
        af[i] = *(const short8*)((const char*)&As[cur][0] + ar * 128 + ((akg ^ (ar & 7)) << 4));
        const int br = wc * 64 + i * 16 + lrow;
        bfr[i] = *(const short8*)((const char*)&Bs[cur][0] + br * 128 + ((akg ^ (br & 7)) << 4));
      }
#pragma unroll
      for (int i = 0; i < 4; ++i)
#pragma unroll
        for (int j = 0; j < 4; ++j)
          acc[i][j] = __builtin_amdgcn_mfma_f32_16x16x32_bf16(af[i], bfr[j], acc[i][j], 0, 0, 0);
    }
    __syncthreads();          // waits vmcnt(0) (prefetch landed) + lgkm
    cur ^= 1;
  }

  const int crow = (lane >> 4) * 4;
  const int ccol = lane & 15;
  if (EPI == 0) {
#pragma unroll
    for (int i = 0; i < 4; ++i)
#pragma unroll
      for (int j = 0; j < 4; ++j)
#pragma unroll
        for (int rg = 0; rg < 4; ++rg) {
          const size_t grow = arow0 + wr * 64 + i * 16 + crow + rg;
          const size_t gcol = bcol0 + wc * 64 + j * 16 + ccol;
          float v = acc[i][j][rg];
          if (R) {
            v += R[grow * Ni + gcol];
            C[grow * Ni + gcol] = v;
          } else {
            __builtin_nontemporal_store(v, &C[grow * Ni + gcol]);
          }
        }
  } else if (EPI == 2) {
    const int sec = (int)(bcol0 >> 10);                       // 0=q,1=k,2=v
    const int hh = (((int)bcol0 & 1023) >> 6) + wc;           // head 0..15
    float* dstQK = (sec == 0) ? QRo : KRo;
#pragma unroll
    for (int i = 0; i < 4; ++i)
#pragma unroll
      for (int rg = 0; rg < 4; ++rg) {
        const int t = (int)arow0 + wr * 64 + i * 16 + crow + rg;
        const int bb = t >> 10, tt = t & 1023;
        const size_t obase = ((size_t)(bb * Hn + hh) * Tn + tt) * 64;
#pragma unroll
        for (int j = 0; j < 4; ++j) {
          const int jd = j * 16 + ccol;
          const float v = acc[i][j][rg];
          if (sec < 2) {
            const float p = acc[i][j ^ 2][rg];
            const float cs = COS[tt * 64 + jd], sn = SIN[tt * 64 + jd];
            dstQK[obase + jd] = v * cs + ((j < 2) ? -p : p) * sn;
          } else {
            VRo[obase + jd] = v;
          }
        }
      }
  } else if (EPI == 3) {
#pragma unroll
    for (int i = 0; i < 4; ++i)
#pragma unroll
      for (int rg = 0; rg < 4; ++rg) {
        const size_t grow = arow0 + wr * 64 + i * 16 + crow + rg;
#pragma unroll
        for (int jp = 0; jp < 2; ++jp) {
          const int j = jp * 2;
          const float a = acc[i][j][rg];
          const float g3 = acc[i][j + 1][rg];
          const float s = (a / (1.f + __expf(-a))) * g3;
          const int f = ((((int)bcol0 + wc * 64 + j * 16) >> 5) << 4) + ccol;
          U[grow * 4096 + f] = f2b(s);
        }
      }
  }
}

// ---------------- block-sparse attention (f32, online softmax) ----------------
__global__ __launch_bounds__(256) void attn_kernel(
    const float* __restrict__ QR, const float* __restrict__ KR, const float* __restrict__ VR,
    const int* __restrict__ sel, u16* __restrict__ O) {
  __shared__ float Qs[32][64], Ks[32][64], Vs[32][64], S[32][32];
  const int blk = blockIdx.x;    // 1024
  const int mq = blk & 31, h = (blk >> 5) & 15, b = blk >> 9;
  const int tid = threadIdx.x;
  const size_t bh = (size_t)(b * Hn + h) * Tn;
  {
    const f4* q4 = (const f4*)(QR + (bh + mq * 32) * 64);
    f4* s4 = (f4*)&Qs[0][0];
    s4[tid] = q4[tid]; s4[tid + 256] = q4[tid + 256];
  }
  const int row = tid >> 3, dg = tid & 7;
  const int dh0 = dg * 8;
  f4 acc0 = {0.f,0.f,0.f,0.f}, acc1 = {0.f,0.f,0.f,0.f};
  float m_i = -3e38f, l_i = 0.f;
  for (int mk = 0; mk <= mq; ++mk) {
    if (!(sel[b * 32 + mk] | (mk == mq))) continue;
    __syncthreads();   // prior-iter reads done; Qs visible on first iter
    {
      const f4* k4 = (const f4*)(KR + (bh + mk * 32) * 64);
      const f4* v4 = (const f4*)(VR + (bh + mk * 32) * 64);
      ((f4*)Ks)[tid] = k4[tid]; ((f4*)Ks)[tid + 256] = k4[tid + 256];
      ((f4*)Vs)[tid] = v4[tid]; ((f4*)Vs)[tid + 256] = v4[tid + 256];
    }
    __syncthreads();
#pragma unroll
    for (int c = 0; c < 4; ++c) {
      const int idx = tid * 4 + c;
      const int qi = idx >> 5, kj = idx & 31;
      const f4* qv = (const f4*)Qs[qi];
      const f4* kv = (const f4*)Ks[kj];
      f4 sv = {0.f,0.f,0.f,0.f};
#pragma unroll
      for (int d = 0; d < 16; ++d) sv += qv[d] * kv[d];
      float s = (sv[0] + sv[1] + sv[2] + sv[3]) * 0.125f;
      if (mk == mq && kj > qi) s = -3e38f;
      S[qi][kj] = s;
    }
    __syncthreads();
    float mx = m_i;
#pragma unroll
    for (int j2 = 0; j2 < 32; ++j2) mx = fmaxf(mx, S[row][j2]);
    const float resc = __expf(m_i - mx);
    float pv[4]; float psum = 0.f;
#pragma unroll
    for (int c = 0; c < 4; ++c) {
      pv[c] = __expf(S[row][dg * 4 + c] - mx);
      psum += pv[c];
    }
    __syncthreads();   // all raw-score reads done
#pragma unroll
    for (int c = 0; c < 4; ++c) S[row][dg * 4 + c] = pv[c];
    psum += __shfl_xor(psum, 1);
    psum += __shfl_xor(psum, 2);
    psum += __shfl_xor(psum, 4);
    l_i = l_i * resc + psum;
    m_i = mx;
    acc0 *= resc; acc1 *= resc;
    __syncthreads();   // p visible
#pragma unroll
    for (int kj = 0; kj < 32; ++kj) {
      const float p = S[row][kj];
      const f4* vv = (const f4*)&Vs[kj][dh0];
      acc0 += vv[0] * p; acc1 += vv[1] * p;
    }
  }
  const float inv = 1.f / l_i;
  us8 o;
#pragma unroll
  for (int e = 0; e < 4; ++e) { o[e] = f2b(acc0[e] * inv); o[4 + e] = f2b(acc1[e] * inv); }
  const int t = mq * 32 + row;
  *(us8*)(O + (size_t)(b * Tn + t) * Dn + h * 64 + dh0) = o;
}

extern "C" void kernel_launch(void* const* d_in, const int* in_sizes, int n_in,
                              void* d_out, int out_size, void* d_ws, size_t ws_size,
                              hipStream_t stream) {
  const int*   ids   = (const int*)d_in[0];
  const float* emb   = (const float*)d_in[1];
  const float* wq    = (const float*)d_in[2];
  const float* wk    = (const float*)d_in[3];
  const float* wv    = (const float*)d_in[4];
  const float* wo    = (const float*)d_in[5];
  const float* w1    = (const float*)d_in[6];
  const float* w2    = (const float*)d_in[7];
  const float* w3    = (const float*)d_in[8];
  const float* anrm  = (const float*)d_in[9];
  const float* fnrm  = (const float*)d_in[10];
  const float* finrm = (const float*)d_in[11];
  const float* lmw   = (const float*)d_in[12];
  float* out = (float*)d_out;

  char* ws = (char*)d_ws;
  size_t off = 0;
  auto alloc = [&](size_t sz) { void* p = ws + off; off += (sz + 255) & ~(size_t)255; return p; };
  const size_t MB = 1024ull * 1024ull;

  float* X    = (float*)alloc((size_t)GM * Dn * 4);      // 8 MiB
  u16*   Hb   = (u16*)alloc((size_t)GM * Dn * 2);        // 4 MiB
  float* COS  = (float*)alloc((size_t)Tn * 64 * 4);      // 256 KiB
  float* SIN  = (float*)alloc((size_t)Tn * 64 * 4);      // 256 KiB
  int*   SEL  = (int*)alloc(256);
  // per-layer converted weights (reused each layer): 32 MiB
  u16*   QKVl = (u16*)alloc((size_t)3072 * 1024 * 2);    // 6 MiB
  u16*   WOl  = (u16*)alloc((size_t)1024 * 1024 * 2);    // 2 MiB
  u16*   W13l = (u16*)alloc((size_t)8192 * 1024 * 2);    // 16 MiB (w1/w3 16-col interleaved)
  u16*   W2l  = (u16*)alloc((size_t)1024 * 4096 * 2);    // 8 MiB
  char*  SCR  = (char*)alloc(66 * MB);                   // phase overlay

  if (off > ws_size) return;  // tripwire: absmax would be exactly 3.796875 (zero out)

  // quality-phase overlays on SCR
  float* Ac  = (float*)SCR;              // 1 MiB
  float* Bc  = (float*)(SCR + 1 * MB);   // 1 MiB
  float* RHO = (float*)(SCR + 2 * MB);   // 8 KiB
  float* PA  = (float*)(SCR + 4 * MB);   // 8 MiB
  float* PB  = (float*)(SCR + 12 * MB);  // 8 MiB
  // attention-phase overlays
  float* QRb  = (float*)(SCR + 24 * MB); // 8 MiB
  float* KRb  = (float*)(SCR + 32 * MB); // 8 MiB
  float* VRb  = (float*)(SCR + 40 * MB); // 8 MiB
  u16*   Ob   = (u16*)(SCR + 48 * MB);   // 4 MiB
  // ffn-phase overlay
  u16*   Ub   = (u16*)(SCR + 0 * MB);    // 16 MiB (silu(g1)*g3, bf16)
  // final-phase overlay (62.5 MiB)
  u16*   LMT  = (u16*)SCR;

  // ---- setup ----
  rope_tab_kernel<<<Tn, 64, 0, stream>>>(COS, SIN);
  embed_kernel<<<GM, 256, 0, stream>>>(ids, emb, X);
  qa_kernel<<<2048, 256, 0, stream>>>(X, PA, PB);
  qa_red_kernel<<<256, 256, 0, stream>>>(PA, PB, Ac, Bc);
  qr_kernel<<<Bn * 256, 256, 0, stream>>>(Ac, Bc, X, RHO);
  topk_kernel<<<Bn, 32, 0, stream>>>(RHO, SEL);

  // ---- layers ----
  for (int l = 0; l < Ln; ++l) {
    const size_t dd = (size_t)1024 * 1024;
    const size_t df = (size_t)1024 * 4096;
    // convert this layer's weights: f32 (K,N) -> bf16 (N,K)
    transpose64<<<dim3(16, 16), 256, 0, stream>>>(wq + l * dd, QKVl, 1024, 1024, 16, 0);
    transpose64<<<dim3(16, 16), 256, 0, stream>>>(wk + l * dd, QKVl + dd, 1024, 1024, 16, 0);
    transpose64<<<dim3(16, 16), 256, 0, stream>>>(wv + l * dd, QKVl + 2 * dd, 1024, 1024, 16, 0);
    transpose64<<<dim3(16, 16), 256, 0, stream>>>(wo + l * dd, WOl, 1024, 1024, 16, 0);
    transpose64<<<dim3(64, 16), 256, 0, stream>>>(w1 + l * df, W13l, 1024, 4096, 32, 0);
    transpose64<<<dim3(64, 16), 256, 0, stream>>>(w3 + l * df, W13l, 1024, 4096, 32, 16);
    transpose64<<<dim3(16, 64), 256, 0, stream>>>(w2 + l * df, W2l, 4096, 1024, 16, 0);

    rmsnorm_kernel<<<GM, 256, 0, stream>>>(X, anrm + l * Dn, Hb);
    // QKV + fused RoPE + head-split
    gemm_bf16<2><<<384, 256, 0, stream>>>(Hb, QKVl, nullptr, nullptr, nullptr,
                                          QRb, KRb, VRb, COS, SIN, 3072, 1024, 0);
    attn_kernel<<<Bn * Hn * 32, 256, 0, stream>>>(QRb, KRb, VRb, SEL, Ob);
    gemm_bf16<0><<<128, 256, 0, stream>>>(Ob, WOl, X, X, nullptr,
                                          nullptr, nullptr, nullptr, nullptr, nullptr, 1024, 1024, 1);
    rmsnorm_kernel<<<GM, 256, 0, stream>>>(X, fnrm + l * Dn, Hb);
    // W1/W3 + fused silu*mul -> Ub (bf16)
    gemm_bf16<3><<<1024, 256, 0, stream>>>(Hb, W13l, nullptr, nullptr, Ub,
                                           nullptr, nullptr, nullptr, nullptr, nullptr, 8192, 1024, 0);
    gemm_bf16<0><<<128, 256, 0, stream>>>(Ub, W2l, X, X, nullptr,
                                          nullptr, nullptr, nullptr, nullptr, nullptr, 1024, 4096, 1);
  }

  // ---- final norm + lm_head ----
  transpose64<<<dim3(500, 16), 256, 0, stream>>>(lmw, LMT, 1024, Vn, 16, 0);
  rmsnorm_kernel<<<GM, 256, 0, stream>>>(X, finrm, Hb);
  gemm_bf16<0><<<4000, 256, 0, stream>>>(Hb, LMT, out, nullptr, nullptr,
                                         nullptr, nullptr, nullptr, nullptr, nullptr, Vn, 1024, 0);
}